// Round 3
// baseline (914.804 us; speedup 1.0000x reference)
//
#include <hip/hip_runtime.h>

// Problem dims
#define NS 64      // batch
#define TT 256     // caption length
#define TS 255     // RNN timesteps (T-1)
#define VV 10000   // vocab
#define DF 1280    // feature dim
#define WD 256     // word-embed dim
#define HD 512     // hidden dim
#define RTOT (TS*NS)   // 16320 output rows (r = t*64 + n)
#define RPAD 16384     // padded rows for hs

typedef __attribute__((ext_vector_type(4))) float f32x4;
typedef __attribute__((ext_vector_type(8))) short s16x8;
typedef __attribute__((ext_vector_type(4))) unsigned int u32x4;

__device__ __forceinline__ unsigned short f2bf(float f){
  unsigned u; __builtin_memcpy(&u, &f, 4);
  u += 0x7FFFu + ((u >> 16) & 1u);            // RNE
  return (unsigned short)(u >> 16);
}
__device__ __forceinline__ float bf2f(unsigned short h){
  unsigned u = ((unsigned)h) << 16; float f; __builtin_memcpy(&f, &u, 4); return f;
}
__device__ __forceinline__ unsigned char f2fp8(float f){
  int p = __builtin_amdgcn_cvt_pk_fp8_f32(f, f, 0, false);  // OCP e4m3
  return (unsigned char)(p & 0xFF);
}
__device__ __forceinline__ float dot4_fp8(unsigned int a, unsigned int b){
  float d;
  d  = __builtin_amdgcn_cvt_f32_fp8(a, 0) * __builtin_amdgcn_cvt_f32_fp8(b, 0);
  d += __builtin_amdgcn_cvt_f32_fp8(a, 1) * __builtin_amdgcn_cvt_f32_fp8(b, 1);
  d += __builtin_amdgcn_cvt_f32_fp8(a, 2) * __builtin_amdgcn_cvt_f32_fp8(b, 2);
  d += __builtin_amdgcn_cvt_f32_fp8(a, 3) * __builtin_amdgcn_cvt_f32_fp8(b, 3);
  return d;
}

// ---------------- K0: transpose + convert weights (fp32 [R][C] -> [C][R] bf16/fp8)
template<int FP8>
__global__ __launch_bounds__(256) void k_transpose_cvt(const float* __restrict__ src,
    unsigned char* __restrict__ dst, int R, int C){
  __shared__ float tile[32][33];
  int r0 = blockIdx.x*32, c0 = blockIdx.y*32;
  int tr = threadIdx.x >> 5, tc = threadIdx.x & 31;
  #pragma unroll
  for(int p=0;p<4;p++){
    int r = r0 + tr + p*8, c = c0 + tc;
    tile[tr + p*8][tc] = (r < R && c < C) ? src[r*C + c] : 0.f;
  }
  __syncthreads();
  #pragma unroll
  for(int p=0;p<4;p++){
    int oc = c0 + tr + p*8;   // dst row (C dim)
    int orow = r0 + tc;       // dst col (R dim)
    if(oc < C && orow < R){
      float v = tile[tc][tr + p*8];
      if(FP8) dst[oc*R + orow] = f2fp8(v);
      else ((unsigned short*)dst)[oc*R + orow] = f2bf(v);
    }
  }
}

// ---------------- K0c: elementwise fp32 -> bf16
__global__ __launch_bounds__(256) void k_cvt_bf16(const float* __restrict__ src,
    unsigned short* __restrict__ dst, int n){
  int i = blockIdx.x*256 + threadIdx.x;
  if(i < n) dst[i] = f2bf(src[i]);
}

// ---------------- K1: h0 = feat @ W_proj + b_proj  -> bf16 [64][512]
__global__ __launch_bounds__(256) void k_h0(const unsigned short* __restrict__ featb,
    const unsigned short* __restrict__ WprojT, const float* __restrict__ b_proj,
    unsigned short* __restrict__ h0b){
  __shared__ unsigned short Al[64*264];
  __shared__ unsigned short Bl[64*264];
  int tid = threadIdx.x, cb = blockIdx.x;
  int w = tid>>6, lane = tid&63, q = lane>>4, rr = lane&15;
  f32x4 acc[4];
  #pragma unroll
  for(int i=0;i<4;i++){ acc[i][0]=0.f; acc[i][1]=0.f; acc[i][2]=0.f; acc[i][3]=0.f; }
  for(int kb=0; kb<5; kb++){
    {
      int row = tid >> 2, part = tid & 3;
      const u32x4* s = (const u32x4*)(featb + row*DF + kb*256 + part*64);
      u32x4* d = (u32x4*)(Al + row*264 + part*64);
      #pragma unroll
      for(int i=0;i<8;i++) d[i] = s[i];
    }
    {
      int row = tid >> 2, part = tid & 3;
      int j = cb*64 + row;
      const u32x4* s = (const u32x4*)(WprojT + j*DF + kb*256 + part*64);
      u32x4* d = (u32x4*)(Bl + row*264 + part*64);
      #pragma unroll
      for(int i=0;i<8;i++) d[i] = s[i];
    }
    __syncthreads();
    #pragma unroll
    for(int kc=0;kc<8;kc++){
      s16x8 a = *(const s16x8*)(Al + (w*16 + rr)*264 + kc*32 + q*8);
      #pragma unroll
      for(int tc=0;tc<4;tc++){
        s16x8 bb = *(const s16x8*)(Bl + (tc*16 + rr)*264 + kc*32 + q*8);
        acc[tc] = __builtin_amdgcn_mfma_f32_16x16x32_bf16(a, bb, acc[tc], 0, 0, 0);
      }
    }
    __syncthreads();
  }
  #pragma unroll
  for(int tc=0;tc<4;tc++){
    #pragma unroll
    for(int reg=0;reg<4;reg++){
      int n = w*16 + q*4 + reg;
      int j = cb*64 + tc*16 + rr;
      h0b[n*HD + j] = f2bf(acc[tc][reg] + b_proj[j]);
    }
  }
}

// ---------------- K2: xW[t][n][j] = W_embed[cap[n][t]] @ Wx + b  -> bf16
__global__ __launch_bounds__(256) void k_xw(const unsigned short* __restrict__ Wembb,
    const unsigned short* __restrict__ WxT, const float* __restrict__ bvec,
    const int* __restrict__ captions, unsigned short* __restrict__ xWb){
  __shared__ unsigned short Al[64*264];
  __shared__ unsigned short Bl[64*264];
  int tid = threadIdx.x, cb = blockIdx.x, t = blockIdx.y;
  int w = tid>>6, lane = tid&63, q = lane>>4, rr = lane&15;
  {
    int row = tid >> 2, part = tid & 3;
    int idx = captions[row*TT + t];
    const u32x4* s = (const u32x4*)(Wembb + idx*WD + part*64);
    u32x4* d = (u32x4*)(Al + row*264 + part*64);
    #pragma unroll
    for(int i=0;i<8;i++) d[i] = s[i];
  }
  {
    int row = tid >> 2, part = tid & 3;
    int j = cb*64 + row;
    const u32x4* s = (const u32x4*)(WxT + j*WD + part*64);
    u32x4* d = (u32x4*)(Bl + row*264 + part*64);
    #pragma unroll
    for(int i=0;i<8;i++) d[i] = s[i];
  }
  __syncthreads();
  f32x4 acc[4];
  #pragma unroll
  for(int i=0;i<4;i++){ acc[i][0]=0.f; acc[i][1]=0.f; acc[i][2]=0.f; acc[i][3]=0.f; }
  #pragma unroll
  for(int kc=0;kc<8;kc++){
    s16x8 a = *(const s16x8*)(Al + (w*16 + rr)*264 + kc*32 + q*8);
    #pragma unroll
    for(int tc=0;tc<4;tc++){
      s16x8 bb = *(const s16x8*)(Bl + (tc*16 + rr)*264 + kc*32 + q*8);
      acc[tc] = __builtin_amdgcn_mfma_f32_16x16x32_bf16(a, bb, acc[tc], 0, 0, 0);
    }
  }
  #pragma unroll
  for(int tc=0;tc<4;tc++){
    #pragma unroll
    for(int reg=0;reg<4;reg++){
      int n = w*16 + q*4 + reg;
      int j = cb*64 + tc*16 + rr;
      xWb[t*(NS*HD) + n*HD + j] = f2bf(acc[tc][reg] + bvec[j]);
    }
  }
}

// ---------------- K3: RNN scan, Wh fp8 resident in VGPRs (128/thread).
// 4 WGs x 16 samples x 512 thr. h fp8 in LDS; xW tiles double-buffered in LDS.
__global__ __launch_bounds__(512, 2) void k_rnn(const unsigned short* __restrict__ h0b,
    const unsigned char* __restrict__ Wh8T, const unsigned short* __restrict__ xWb,
    unsigned char* __restrict__ hs8){
  __shared__ unsigned char hbuf[16*528];       // fp8 h [sample][col], stride 528
  __shared__ unsigned short xwl[2][16*512];    // 16KB x2 xw tiles
  int tid = threadIdx.x, w = tid>>6, lane = tid&63, q = lane>>4, rr = lane&15;
  int n0 = blockIdx.x * 16;
  int j0 = w * 64;                             // 8 waves x 64 cols
  // preload Wh B-frags: 64 longs = 128 VGPRs (256 KB/WG, once)
  long whB[4][16];
  #pragma unroll
  for(int ct=0;ct<4;ct++)
    #pragma unroll
    for(int kc=0;kc<16;kc++)
      whB[ct][kc] = *(const long*)(Wh8T + (j0+ct*16+rr)*HD + kc*32 + q*8);
  // init h (bf16 -> fp8)
  {
    int s = tid>>5, c0 = (tid&31)*16;
    #pragma unroll
    for(int i=0;i<16;i++)
      hbuf[s*528 + c0 + i] = f2fp8(bf2f(h0b[(n0+s)*HD + c0 + i]));
  }
  // stage xw tile t=0
  {
    const u32x4* sp = (const u32x4*)(xWb + n0*HD + tid*16);
    u32x4 a = sp[0], b = sp[1];
    u32x4* dp = (u32x4*)(&xwl[0][tid*16]);
    dp[0]=a; dp[1]=b;
  }
  __syncthreads();
  for(int t=0; t<TS; t++){
    int buf = t & 1;
    long af[16];
    #pragma unroll
    for(int kc=0;kc<16;kc++)
      af[kc] = *(const long*)(hbuf + rr*528 + kc*32 + q*8);
    // prefetch next xw tile into regs (hides HBM latency)
    int tp = (t+1 < TS) ? t+1 : t;
    const u32x4* sp = (const u32x4*)(xWb + (size_t)tp*(NS*HD) + n0*HD + tid*16);
    u32x4 xr0 = sp[0], xr1 = sp[1];
    f32x4 acc[4];
    #pragma unroll
    for(int ct=0;ct<4;ct++){ acc[ct][0]=0.f; acc[ct][1]=0.f; acc[ct][2]=0.f; acc[ct][3]=0.f; }
    #pragma unroll
    for(int kc=0;kc<16;kc++)
      #pragma unroll
      for(int ct=0;ct<4;ct++)
        acc[ct] = __builtin_amdgcn_mfma_f32_16x16x32_fp8_fp8(af[kc], whB[ct][kc], acc[ct], 0, 0, 0);
    unsigned char h8[16];
    #pragma unroll
    for(int ct=0;ct<4;ct++){
      int j = j0 + ct*16 + rr;
      #pragma unroll
      for(int reg=0;reg<4;reg++){
        int nl = q*4 + reg;
        float xw = bf2f(xwl[buf][nl*512 + j]);
        float pre = acc[ct][reg] + xw;
        float e2 = __builtin_amdgcn_exp2f(pre * 2.8853900817779268f); // e^(2x)
        float h = (e2 - 1.f) * __builtin_amdgcn_rcpf(e2 + 1.f);       // tanh
        unsigned char c = f2fp8(h);
        h8[ct*4+reg] = c;
        hs8[(size_t)(t*NS + n0 + nl)*HD + j] = c;
      }
    }
    __syncthreads();   // all waves done reading old h
    #pragma unroll
    for(int ct=0;ct<4;ct++){
      int j = j0 + ct*16 + rr;
      #pragma unroll
      for(int reg=0;reg<4;reg++)
        hbuf[(q*4+reg)*528 + j] = h8[ct*4+reg];
    }
    {
      u32x4* dp = (u32x4*)(&xwl[buf^1][tid*16]);
      dp[0]=xr0; dp[1]=xr1;
    }
    __syncthreads();   // new h + next xw tile visible
  }
}

// ---------------- K4: fused scores GEMM (fp8) + sumexp partials.
// grid (4 chunks, 256 rowblocks of 64); 256 thr; 64-row B tiles -> 4 blocks/CU.
__global__ __launch_bounds__(256, 4) void k_scores(const unsigned char* __restrict__ hs8,
    const unsigned char* __restrict__ WoutT, const float* __restrict__ b_out,
    float* __restrict__ partial_s){
  __shared__ unsigned char Bl[64*528];
  __shared__ float sred[2][64];
  int tid = threadIdx.x;
  int chunk = blockIdx.x, rb = blockIdx.y;
  int w = tid>>6, lane = tid&63, q = lane>>4, rr = lane&15;
  int wi = w>>1, wj = w&1;          // wi: row half (32), wj: col half (32)
  long af[2][16];
  #pragma unroll
  for(int tr=0;tr<2;tr++)
    #pragma unroll
    for(int kc=0;kc<16;kc++){
      int row = rb*64 + wi*32 + tr*16 + rr;   // < RPAD always
      af[tr][kc] = *(const long*)(hs8 + (size_t)row*HD + kc*32 + q*8);
    }
  float sacc[8];
  #pragma unroll
  for(int i=0;i<8;i++) sacc[i]=0.f;
  int vc0 = chunk*2500, vc1 = vc0 + 2500;
  for(int vt=0; vt<40; vt++){
    int vbase = vc0 + vt*64;
    {
      int v = tid & 63, part = tid >> 6;
      int vg = vbase + v; if(vg > VV-1) vg = VV-1;
      const u32x4* s = (const u32x4*)(WoutT + (size_t)vg*HD + part*128);
      u32x4 t0=s[0],t1=s[1],t2=s[2],t3=s[3],t4=s[4],t5=s[5],t6=s[6],t7=s[7];
      u32x4* d = (u32x4*)(Bl + v*528 + part*128);
      d[0]=t0;d[1]=t1;d[2]=t2;d[3]=t3;d[4]=t4;d[5]=t5;d[6]=t6;d[7]=t7;
    }
    __syncthreads();
    f32x4 acc[2][2];
    #pragma unroll
    for(int a=0;a<2;a++)
      #pragma unroll
      for(int b=0;b<2;b++){ acc[a][b][0]=0.f; acc[a][b][1]=0.f; acc[a][b][2]=0.f; acc[a][b][3]=0.f; }
    #pragma unroll
    for(int kc=0;kc<16;kc++){
      long b0 = *(const long*)(Bl + (wj*32 +  0 + rr)*528 + kc*32 + q*8);
      long b1 = *(const long*)(Bl + (wj*32 + 16 + rr)*528 + kc*32 + q*8);
      acc[0][0] = __builtin_amdgcn_mfma_f32_16x16x32_fp8_fp8(af[0][kc], b0, acc[0][0], 0,0,0);
      acc[0][1] = __builtin_amdgcn_mfma_f32_16x16x32_fp8_fp8(af[0][kc], b1, acc[0][1], 0,0,0);
      acc[1][0] = __builtin_amdgcn_mfma_f32_16x16x32_fp8_fp8(af[1][kc], b0, acc[1][0], 0,0,0);
      acc[1][1] = __builtin_amdgcn_mfma_f32_16x16x32_fp8_fp8(af[1][kc], b1, acc[1][1], 0,0,0);
    }
    #pragma unroll
    for(int tc=0;tc<2;tc++){
      int vg = vbase + wj*32 + tc*16 + rr;
      bool vok = vg < vc1;
      float bo = vok ? b_out[vg] : 0.f;
      #pragma unroll
      for(int tr=0;tr<2;tr++)
        #pragma unroll
        for(int reg=0;reg<4;reg++){
          float sc = acc[tr][tc][reg] + bo;
          float ex = __builtin_amdgcn_exp2f(sc * 1.4426950408889634f);
          if(vok) sacc[tr*4+reg] += ex;
        }
    }
    __syncthreads();
  }
  #pragma unroll
  for(int i=0;i<8;i++){
    float v = sacc[i];
    v += __shfl_xor(v, 1, 64);
    v += __shfl_xor(v, 2, 64);
    v += __shfl_xor(v, 4, 64);
    v += __shfl_xor(v, 8, 64);
    sacc[i] = v;
  }
  if(rr == 0){
    #pragma unroll
    for(int tr=0;tr<2;tr++)
      #pragma unroll
      for(int reg=0;reg<4;reg++)
        sred[wj][wi*32 + tr*16 + q*4 + reg] = sacc[tr*4+reg];
  }
  __syncthreads();
  if(tid < 64){
    int row = rb*64 + tid;
    if(row < RTOT) partial_s[row*4 + chunk] = sred[0][tid] + sred[1][tid];
  }
}

// ---------------- K4b: picked[R] = score(R, y_R) ; one wave per row
__global__ __launch_bounds__(256) void k_picked(const unsigned char* __restrict__ hs8,
    const unsigned char* __restrict__ WoutT, const float* __restrict__ b_out,
    const int* __restrict__ captions, float* __restrict__ picked){
  int tid = threadIdx.x;
  int w = tid>>6, lane = tid&63;
  int R = blockIdx.x*4 + w;                 // 4080*4 = 16320 exact
  int t = R >> 6, n = R & 63;
  int y = captions[n*TT + t + 1];
  const unsigned int* hp = (const unsigned int*)(hs8 + (size_t)R*HD + lane*8);
  const unsigned int* wp = (const unsigned int*)(WoutT + (size_t)y*HD + lane*8);
  unsigned int hv0 = hp[0], hv1 = hp[1], wv0 = wp[0], wv1 = wp[1];
  float d = dot4_fp8(hv0, wv0) + dot4_fp8(hv1, wv1);
  d += __shfl_xor(d, 1, 64);
  d += __shfl_xor(d, 2, 64);
  d += __shfl_xor(d, 4, 64);
  d += __shfl_xor(d, 8, 64);
  d += __shfl_xor(d, 16, 64);
  d += __shfl_xor(d, 32, 64);
  if(lane == 0) picked[R] = d + b_out[y];
}

// ---------------- K5: loss = sum_masked(log(sum_s) - picked) / 64
__global__ __launch_bounds__(256) void k_loss(const float* __restrict__ partial_s,
    const float* __restrict__ picked, const int* __restrict__ captions,
    float* __restrict__ out){
  int tid = threadIdx.x;
  float a = 0.f;
  for(int R = tid; R < RTOT; R += 256){
    int t = R >> 6, n = R & 63;
    int y = captions[n*TT + t + 1];
    if(y != 0){
      float s = partial_s[R*4] + partial_s[R*4+1] + partial_s[R*4+2] + partial_s[R*4+3];
      a += __logf(s) - picked[R];
    }
  }
  a += __shfl_xor(a, 1, 64);
  a += __shfl_xor(a, 2, 64);
  a += __shfl_xor(a, 4, 64);
  a += __shfl_xor(a, 8, 64);
  a += __shfl_xor(a, 16, 64);
  a += __shfl_xor(a, 32, 64);
  __shared__ float red[4];
  int w = tid>>6, lane = tid&63;
  if(lane == 0) red[w] = a;
  __syncthreads();
  if(tid == 0) out[0] = (red[0]+red[1]+red[2]+red[3]) * (1.0f/64.0f);
}

extern "C" void kernel_launch(void* const* d_in, const int* in_sizes, int n_in,
                              void* d_out, int out_size, void* d_ws, size_t ws_size,
                              hipStream_t stream) {
  const float* feat    = (const float*)d_in[0];
  const float* W_proj  = (const float*)d_in[1];
  const float* b_proj  = (const float*)d_in[2];
  const float* W_embed = (const float*)d_in[3];
  const float* Wx      = (const float*)d_in[4];
  const float* Wh      = (const float*)d_in[5];
  const float* bvec    = (const float*)d_in[6];
  const float* W_out   = (const float*)d_in[7];
  const float* b_out   = (const float*)d_in[8];
  const int*   captions= (const int*)d_in[9];

  char* p = (char*)d_ws;
  unsigned short* WprojT = (unsigned short*)p;  p += 512*1280*2;    // 1,310,720
  unsigned short* WxT    = (unsigned short*)p;  p += 512*256*2;     //   262,144
  unsigned char*  Wh8T   = (unsigned char*)p;   p += 512*512;       //   262,144
  unsigned char*  WoutT  = (unsigned char*)p;   p += 10000*512;     // 5,120,000
  unsigned short* Wembb  = (unsigned short*)p;  p += 10000*256*2;   // 5,120,000
  unsigned short* featb  = (unsigned short*)p;  p += 64*1280*2;     //   163,840
  unsigned short* h0b    = (unsigned short*)p;  p += 64*512*2;      //    65,536
  unsigned short* xWb    = (unsigned short*)p;  p += TS*64*512*2;   //16,711,680
  unsigned char*  hs8    = (unsigned char*)p;   p += RPAD*512;      // 8,388,608
  float* partial_s       = (float*)p;           p += RTOT*4*4;      //   261,120
  float* picked          = (float*)p;           p += RTOT*4;        //    65,280
  if((size_t)(p - (char*)d_ws) > ws_size) return;  // workspace too small

  // K0: weight conversions
  k_transpose_cvt<0><<<dim3(40,16), 256, 0, stream>>>(W_proj, (unsigned char*)WprojT, 1280, 512);
  k_transpose_cvt<0><<<dim3(8,16),  256, 0, stream>>>(Wx,     (unsigned char*)WxT,    256,  512);
  k_transpose_cvt<1><<<dim3(16,16), 256, 0, stream>>>(Wh,     Wh8T,                   512,  512);
  k_transpose_cvt<1><<<dim3(16,313),256, 0, stream>>>(W_out,  WoutT,                  512,  10000);
  k_cvt_bf16<<<320,   256, 0, stream>>>(feat,    featb, 64*1280);
  k_cvt_bf16<<<10000, 256, 0, stream>>>(W_embed, Wembb, 10000*256);

  // K1: h0
  k_h0<<<8, 256, 0, stream>>>(featb, WprojT, b_proj, h0b);
  // K2: xW
  k_xw<<<dim3(8, TS), 256, 0, stream>>>(Wembb, WxT, bvec, captions, xWb);
  // K3: RNN scan (Wh fp8 in VGPRs)
  k_rnn<<<4, 512, 0, stream>>>(h0b, Wh8T, xWb, hs8);
  // K4: fused scores + sumexp partials
  k_scores<<<dim3(4, 256), 256, 0, stream>>>(hs8, WoutT, b_out, partial_s);
  // K4b: picked scores
  k_picked<<<4080, 256, 0, stream>>>(hs8, WoutT, b_out, captions, picked);
  // K5: final loss
  k_loss<<<1, 256, 0, stream>>>(partial_s, picked, captions, (float*)d_out);
}

// Round 4
// 890.105 us; speedup vs baseline: 1.0277x; 1.0277x over previous
//
#include <hip/hip_runtime.h>

// Problem dims
#define NS 64      // batch
#define TT 256     // caption length
#define TS 255     // RNN timesteps (T-1)
#define VV 10000   // vocab
#define DF 1280    // feature dim
#define WD 256     // word-embed dim
#define HD 512     // hidden dim
#define RTOT (TS*NS)   // 16320 output rows (r = t*64 + n)
#define RPAD 16384     // padded rows for hs

typedef __attribute__((ext_vector_type(4))) float f32x4;
typedef __attribute__((ext_vector_type(8))) short s16x8;
typedef __attribute__((ext_vector_type(4))) unsigned int u32x4;
typedef __attribute__((ext_vector_type(2))) long s64x2;

__device__ __forceinline__ unsigned short f2bf(float f){
  unsigned u; __builtin_memcpy(&u, &f, 4);
  u += 0x7FFFu + ((u >> 16) & 1u);            // RNE
  return (unsigned short)(u >> 16);
}
__device__ __forceinline__ float bf2f(unsigned short h){
  unsigned u = ((unsigned)h) << 16; float f; __builtin_memcpy(&f, &u, 4); return f;
}
__device__ __forceinline__ unsigned char f2fp8(float f){
  int p = __builtin_amdgcn_cvt_pk_fp8_f32(f, f, 0, false);  // OCP e4m3
  return (unsigned char)(p & 0xFF);
}
__device__ __forceinline__ float dot4_fp8(unsigned int a, unsigned int b){
  float d;
  d  = __builtin_amdgcn_cvt_f32_fp8(a, 0) * __builtin_amdgcn_cvt_f32_fp8(b, 0);
  d += __builtin_amdgcn_cvt_f32_fp8(a, 1) * __builtin_amdgcn_cvt_f32_fp8(b, 1);
  d += __builtin_amdgcn_cvt_f32_fp8(a, 2) * __builtin_amdgcn_cvt_f32_fp8(b, 2);
  d += __builtin_amdgcn_cvt_f32_fp8(a, 3) * __builtin_amdgcn_cvt_f32_fp8(b, 3);
  return d;
}

// ---------------- K0: transpose + convert weights (fp32 [R][C] -> [C][R] bf16/fp8)
template<int FP8>
__global__ __launch_bounds__(256) void k_transpose_cvt(const float* __restrict__ src,
    unsigned char* __restrict__ dst, int R, int C){
  __shared__ float tile[32][33];
  int r0 = blockIdx.x*32, c0 = blockIdx.y*32;
  int tr = threadIdx.x >> 5, tc = threadIdx.x & 31;
  #pragma unroll
  for(int p=0;p<4;p++){
    int r = r0 + tr + p*8, c = c0 + tc;
    tile[tr + p*8][tc] = (r < R && c < C) ? src[r*C + c] : 0.f;
  }
  __syncthreads();
  #pragma unroll
  for(int p=0;p<4;p++){
    int oc = c0 + tr + p*8;   // dst row (C dim)
    int orow = r0 + tc;       // dst col (R dim)
    if(oc < C && orow < R){
      float v = tile[tc][tr + p*8];
      if(FP8) dst[oc*R + orow] = f2fp8(v);
      else ((unsigned short*)dst)[oc*R + orow] = f2bf(v);
    }
  }
}

// ---------------- K0w: Wh fp32 [k][j] -> Wh8F fp8 frag-major: row j, pos q*128+kc*8+b
// where k = kc*32 + q*8 + b. Enables dwordx4 B-frag-pair loads in K3.
__global__ __launch_bounds__(256) void k_cvt_whF(const float* __restrict__ Wh,
    unsigned char* __restrict__ Wh8F){
  int j = blockIdx.x;          // 512 blocks
  int k2 = threadIdx.x;        // 256 threads, 2 k each
  #pragma unroll
  for(int i=0;i<2;i++){
    int k = k2*2 + i;
    int p = ((k>>3)&3)*128 + (k>>5)*8 + (k&7);
    Wh8F[j*HD + p] = f2fp8(Wh[k*HD + j]);
  }
}

// ---------------- K0c: elementwise fp32 -> bf16
__global__ __launch_bounds__(256) void k_cvt_bf16(const float* __restrict__ src,
    unsigned short* __restrict__ dst, int n){
  int i = blockIdx.x*256 + threadIdx.x;
  if(i < n) dst[i] = f2bf(src[i]);
}

// ---------------- K1: h0 = feat @ W_proj + b_proj  -> bf16 [64][512]
__global__ __launch_bounds__(256) void k_h0(const unsigned short* __restrict__ featb,
    const unsigned short* __restrict__ WprojT, const float* __restrict__ b_proj,
    unsigned short* __restrict__ h0b){
  __shared__ unsigned short Al[64*264];
  __shared__ unsigned short Bl[64*264];
  int tid = threadIdx.x, cb = blockIdx.x;
  int w = tid>>6, lane = tid&63, q = lane>>4, rr = lane&15;
  f32x4 acc[4];
  #pragma unroll
  for(int i=0;i<4;i++){ acc[i][0]=0.f; acc[i][1]=0.f; acc[i][2]=0.f; acc[i][3]=0.f; }
  for(int kb=0; kb<5; kb++){
    {
      int row = tid >> 2, part = tid & 3;
      const u32x4* s = (const u32x4*)(featb + row*DF + kb*256 + part*64);
      u32x4* d = (u32x4*)(Al + row*264 + part*64);
      #pragma unroll
      for(int i=0;i<8;i++) d[i] = s[i];
    }
    {
      int row = tid >> 2, part = tid & 3;
      int j = cb*64 + row;
      const u32x4* s = (const u32x4*)(WprojT + j*DF + kb*256 + part*64);
      u32x4* d = (u32x4*)(Bl + row*264 + part*64);
      #pragma unroll
      for(int i=0;i<8;i++) d[i] = s[i];
    }
    __syncthreads();
    #pragma unroll
    for(int kc=0;kc<8;kc++){
      s16x8 a = *(const s16x8*)(Al + (w*16 + rr)*264 + kc*32 + q*8);
      #pragma unroll
      for(int tc=0;tc<4;tc++){
        s16x8 bb = *(const s16x8*)(Bl + (tc*16 + rr)*264 + kc*32 + q*8);
        acc[tc] = __builtin_amdgcn_mfma_f32_16x16x32_bf16(a, bb, acc[tc], 0, 0, 0);
      }
    }
    __syncthreads();
  }
  #pragma unroll
  for(int tc=0;tc<4;tc++){
    #pragma unroll
    for(int reg=0;reg<4;reg++){
      int n = w*16 + q*4 + reg;
      int j = cb*64 + tc*16 + rr;
      h0b[n*HD + j] = f2bf(acc[tc][reg] + b_proj[j]);
    }
  }
}

// ---------------- K2: xW[t][n][j] = W_embed[cap[n][t]] @ Wx + b  -> bf16
__global__ __launch_bounds__(256) void k_xw(const unsigned short* __restrict__ Wembb,
    const unsigned short* __restrict__ WxT, const float* __restrict__ bvec,
    const int* __restrict__ captions, unsigned short* __restrict__ xWb){
  __shared__ unsigned short Al[64*264];
  __shared__ unsigned short Bl[64*264];
  int tid = threadIdx.x, cb = blockIdx.x, t = blockIdx.y;
  int w = tid>>6, lane = tid&63, q = lane>>4, rr = lane&15;
  {
    int row = tid >> 2, part = tid & 3;
    int idx = captions[row*TT + t];
    const u32x4* s = (const u32x4*)(Wembb + idx*WD + part*64);
    u32x4* d = (u32x4*)(Al + row*264 + part*64);
    #pragma unroll
    for(int i=0;i<8;i++) d[i] = s[i];
  }
  {
    int row = tid >> 2, part = tid & 3;
    int j = cb*64 + row;
    const u32x4* s = (const u32x4*)(WxT + j*WD + part*64);
    u32x4* d = (u32x4*)(Bl + row*264 + part*64);
    #pragma unroll
    for(int i=0;i<8;i++) d[i] = s[i];
  }
  __syncthreads();
  f32x4 acc[4];
  #pragma unroll
  for(int i=0;i<4;i++){ acc[i][0]=0.f; acc[i][1]=0.f; acc[i][2]=0.f; acc[i][3]=0.f; }
  #pragma unroll
  for(int kc=0;kc<8;kc++){
    s16x8 a = *(const s16x8*)(Al + (w*16 + rr)*264 + kc*32 + q*8);
    #pragma unroll
    for(int tc=0;tc<4;tc++){
      s16x8 bb = *(const s16x8*)(Bl + (tc*16 + rr)*264 + kc*32 + q*8);
      acc[tc] = __builtin_amdgcn_mfma_f32_16x16x32_bf16(a, bb, acc[tc], 0, 0, 0);
    }
  }
  #pragma unroll
  for(int tc=0;tc<4;tc++){
    #pragma unroll
    for(int reg=0;reg<4;reg++){
      int n = w*16 + q*4 + reg;
      int j = cb*64 + tc*16 + rr;
      xWb[t*(NS*HD) + n*HD + j] = f2bf(acc[tc][reg] + bvec[j]);
    }
  }
}

// ---------------- K3: RNN scan. fp8 Wh streamed L2->VGPR in-loop (dwordx4 frag pairs).
// 4 WGs x 16 samples x 512 thr. h fp8 double-buffered in LDS (1 barrier/step).
// xw read per-thread directly from global (16 B16 loads, prefetched at step start).
__global__ __launch_bounds__(512, 2) void k_rnn(const unsigned short* __restrict__ h0b,
    const unsigned char* __restrict__ Wh8F, const unsigned short* __restrict__ xWb,
    unsigned char* __restrict__ hs8){
  __shared__ unsigned char hbuf[2][16*552];    // stride 552 B: b64 reads 8-aligned, banks spread
  int tid = threadIdx.x, w = tid>>6, lane = tid&63, q = lane>>4, rr = lane&15;
  int n0 = blockIdx.x * 16;
  int j0 = w * 64;                             // 8 waves x 64 cols
  // init h (bf16 -> fp8) into hbuf[0]
  {
    int s = tid>>5, c0 = (tid&31)*16;
    #pragma unroll
    for(int i=0;i<16;i++)
      hbuf[0][s*552 + c0 + i] = f2fp8(bf2f(h0b[(n0+s)*HD + c0 + i]));
  }
  __syncthreads();
  const unsigned short* xwp = xWb + n0*HD;
  for(int t=0; t<TS; t++){
    const unsigned char* hb = hbuf[t&1];
    unsigned char*       hn = hbuf[(t&1)^1];
    long af[16];
    #pragma unroll
    for(int kc=0;kc<16;kc++)
      af[kc] = *(const long*)(hb + rr*552 + kc*32 + q*8);
    // xw for this step: 16 scalar bf16 loads, needed only in epilogue (full step to cover)
    float xwv[16];
    #pragma unroll
    for(int ct=0;ct<4;ct++)
      #pragma unroll
      for(int reg=0;reg<4;reg++)
        xwv[ct*4+reg] = bf2f(xwp[(q*4+reg)*HD + j0 + ct*16 + rr]);
    f32x4 acc[4];
    #pragma unroll
    for(int ct=0;ct<4;ct++){ acc[ct][0]=0.f; acc[ct][1]=0.f; acc[ct][2]=0.f; acc[ct][3]=0.f; }
    #pragma unroll
    for(int ct=0;ct<4;ct++){
      const s64x2* wp = (const s64x2*)(Wh8F + (size_t)(j0 + ct*16 + rr)*HD + q*128);
      #pragma unroll
      for(int kcp=0;kcp<8;kcp++){
        s64x2 wv = wp[kcp];                    // frags kc=2kcp, 2kcp+1 at quad q
        acc[ct] = __builtin_amdgcn_mfma_f32_16x16x32_fp8_fp8(af[2*kcp],   wv[0], acc[ct], 0,0,0);
        acc[ct] = __builtin_amdgcn_mfma_f32_16x16x32_fp8_fp8(af[2*kcp+1], wv[1], acc[ct], 0,0,0);
      }
    }
    #pragma unroll
    for(int ct=0;ct<4;ct++){
      int j = j0 + ct*16 + rr;
      #pragma unroll
      for(int reg=0;reg<4;reg++){
        int nl = q*4 + reg;
        float pre = acc[ct][reg] + xwv[ct*4+reg];
        float e2 = __builtin_amdgcn_exp2f(pre * 2.8853900817779268f); // e^(2x)
        float h = (e2 - 1.f) * __builtin_amdgcn_rcpf(e2 + 1.f);       // tanh
        unsigned char c = f2fp8(h);
        hs8[(size_t)(t*NS + n0 + nl)*HD + j] = c;
        hn[nl*552 + j] = c;
      }
    }
    __syncthreads();   // hn complete; hb reads of this step done before next step writes it
    xwp += NS*HD;
  }
}

// ---------------- K4: fused scores GEMM (fp8) + sumexp partials.
// grid (4 chunks, 256 rowblocks of 64); 256 thr; 64-row B tiles -> 4 blocks/CU.
__global__ __launch_bounds__(256, 4) void k_scores(const unsigned char* __restrict__ hs8,
    const unsigned char* __restrict__ WoutT, const float* __restrict__ b_out,
    float* __restrict__ partial_s){
  __shared__ unsigned char Bl[64*528];
  __shared__ float sred[2][64];
  int tid = threadIdx.x;
  int chunk = blockIdx.x, rb = blockIdx.y;
  int w = tid>>6, lane = tid&63, q = lane>>4, rr = lane&15;
  int wi = w>>1, wj = w&1;          // wi: row half (32), wj: col half (32)
  long af[2][16];
  #pragma unroll
  for(int tr=0;tr<2;tr++)
    #pragma unroll
    for(int kc=0;kc<16;kc++){
      int row = rb*64 + wi*32 + tr*16 + rr;   // < RPAD always
      af[tr][kc] = *(const long*)(hs8 + (size_t)row*HD + kc*32 + q*8);
    }
  float sacc[8];
  #pragma unroll
  for(int i=0;i<8;i++) sacc[i]=0.f;
  int vc0 = chunk*2500, vc1 = vc0 + 2500;
  for(int vt=0; vt<40; vt++){
    int vbase = vc0 + vt*64;
    {
      int v = tid & 63, part = tid >> 6;
      int vg = vbase + v; if(vg > VV-1) vg = VV-1;
      const u32x4* s = (const u32x4*)(WoutT + (size_t)vg*HD + part*128);
      u32x4 t0=s[0],t1=s[1],t2=s[2],t3=s[3],t4=s[4],t5=s[5],t6=s[6],t7=s[7];
      u32x4* d = (u32x4*)(Bl + v*528 + part*128);
      d[0]=t0;d[1]=t1;d[2]=t2;d[3]=t3;d[4]=t4;d[5]=t5;d[6]=t6;d[7]=t7;
    }
    __syncthreads();
    f32x4 acc[2][2];
    #pragma unroll
    for(int a=0;a<2;a++)
      #pragma unroll
      for(int b=0;b<2;b++){ acc[a][b][0]=0.f; acc[a][b][1]=0.f; acc[a][b][2]=0.f; acc[a][b][3]=0.f; }
    #pragma unroll
    for(int kc=0;kc<16;kc++){
      long b0 = *(const long*)(Bl + (wj*32 +  0 + rr)*528 + kc*32 + q*8);
      long b1 = *(const long*)(Bl + (wj*32 + 16 + rr)*528 + kc*32 + q*8);
      acc[0][0] = __builtin_amdgcn_mfma_f32_16x16x32_fp8_fp8(af[0][kc], b0, acc[0][0], 0,0,0);
      acc[0][1] = __builtin_amdgcn_mfma_f32_16x16x32_fp8_fp8(af[0][kc], b1, acc[0][1], 0,0,0);
      acc[1][0] = __builtin_amdgcn_mfma_f32_16x16x32_fp8_fp8(af[1][kc], b0, acc[1][0], 0,0,0);
      acc[1][1] = __builtin_amdgcn_mfma_f32_16x16x32_fp8_fp8(af[1][kc], b1, acc[1][1], 0,0,0);
    }
    #pragma unroll
    for(int tc=0;tc<2;tc++){
      int vg = vbase + wj*32 + tc*16 + rr;
      bool vok = vg < vc1;
      float bo = vok ? b_out[vg] : 0.f;
      #pragma unroll
      for(int tr=0;tr<2;tr++)
        #pragma unroll
        for(int reg=0;reg<4;reg++){
          float sc = acc[tr][tc][reg] + bo;
          float ex = __builtin_amdgcn_exp2f(sc * 1.4426950408889634f);
          if(vok) sacc[tr*4+reg] += ex;
        }
    }
    __syncthreads();
  }
  #pragma unroll
  for(int i=0;i<8;i++){
    float v = sacc[i];
    v += __shfl_xor(v, 1, 64);
    v += __shfl_xor(v, 2, 64);
    v += __shfl_xor(v, 4, 64);
    v += __shfl_xor(v, 8, 64);
    sacc[i] = v;
  }
  if(rr == 0){
    #pragma unroll
    for(int tr=0;tr<2;tr++)
      #pragma unroll
      for(int reg=0;reg<4;reg++)
        sred[wj][wi*32 + tr*16 + q*4 + reg] = sacc[tr*4+reg];
  }
  __syncthreads();
  if(tid < 64){
    int row = rb*64 + tid;
    if(row < RTOT) partial_s[row*4 + chunk] = sred[0][tid] + sred[1][tid];
  }
}

// ---------------- K4b: picked[R] = score(R, y_R) ; one wave per row
__global__ __launch_bounds__(256) void k_picked(const unsigned char* __restrict__ hs8,
    const unsigned char* __restrict__ WoutT, const float* __restrict__ b_out,
    const int* __restrict__ captions, float* __restrict__ picked){
  int tid = threadIdx.x;
  int w = tid>>6, lane = tid&63;
  int R = blockIdx.x*4 + w;                 // 4080*4 = 16320 exact
  int t = R >> 6, n = R & 63;
  int y = captions[n*TT + t + 1];
  const unsigned int* hp = (const unsigned int*)(hs8 + (size_t)R*HD + lane*8);
  const unsigned int* wp = (const unsigned int*)(WoutT + (size_t)y*HD + lane*8);
  unsigned int hv0 = hp[0], hv1 = hp[1], wv0 = wp[0], wv1 = wp[1];
  float d = dot4_fp8(hv0, wv0) + dot4_fp8(hv1, wv1);
  d += __shfl_xor(d, 1, 64);
  d += __shfl_xor(d, 2, 64);
  d += __shfl_xor(d, 4, 64);
  d += __shfl_xor(d, 8, 64);
  d += __shfl_xor(d, 16, 64);
  d += __shfl_xor(d, 32, 64);
  if(lane == 0) picked[R] = d + b_out[y];
}

// ---------------- K5: loss = sum_masked(log(sum_s) - picked) / 64
__global__ __launch_bounds__(256) void k_loss(const float* __restrict__ partial_s,
    const float* __restrict__ picked, const int* __restrict__ captions,
    float* __restrict__ out){
  int tid = threadIdx.x;
  float a = 0.f;
  for(int R = tid; R < RTOT; R += 256){
    int t = R >> 6, n = R & 63;
    int y = captions[n*TT + t + 1];
    if(y != 0){
      float s = partial_s[R*4] + partial_s[R*4+1] + partial_s[R*4+2] + partial_s[R*4+3];
      a += __logf(s) - picked[R];
    }
  }
  a += __shfl_xor(a, 1, 64);
  a += __shfl_xor(a, 2, 64);
  a += __shfl_xor(a, 4, 64);
  a += __shfl_xor(a, 8, 64);
  a += __shfl_xor(a, 16, 64);
  a += __shfl_xor(a, 32, 64);
  __shared__ float red[4];
  int w = tid>>6, lane = tid&63;
  if(lane == 0) red[w] = a;
  __syncthreads();
  if(tid == 0) out[0] = (red[0]+red[1]+red[2]+red[3]) * (1.0f/64.0f);
}

extern "C" void kernel_launch(void* const* d_in, const int* in_sizes, int n_in,
                              void* d_out, int out_size, void* d_ws, size_t ws_size,
                              hipStream_t stream) {
  const float* feat    = (const float*)d_in[0];
  const float* W_proj  = (const float*)d_in[1];
  const float* b_proj  = (const float*)d_in[2];
  const float* W_embed = (const float*)d_in[3];
  const float* Wx      = (const float*)d_in[4];
  const float* Wh      = (const float*)d_in[5];
  const float* bvec    = (const float*)d_in[6];
  const float* W_out   = (const float*)d_in[7];
  const float* b_out   = (const float*)d_in[8];
  const int*   captions= (const int*)d_in[9];

  char* p = (char*)d_ws;
  unsigned short* WprojT = (unsigned short*)p;  p += 512*1280*2;    // 1,310,720
  unsigned short* WxT    = (unsigned short*)p;  p += 512*256*2;     //   262,144
  unsigned char*  Wh8F   = (unsigned char*)p;   p += 512*512;       //   262,144
  unsigned char*  WoutT  = (unsigned char*)p;   p += 10000*512;     // 5,120,000
  unsigned short* Wembb  = (unsigned short*)p;  p += 10000*256*2;   // 5,120,000
  unsigned short* featb  = (unsigned short*)p;  p += 64*1280*2;     //   163,840
  unsigned short* h0b    = (unsigned short*)p;  p += 64*512*2;      //    65,536
  unsigned short* xWb    = (unsigned short*)p;  p += TS*64*512*2;   //16,711,680
  unsigned char*  hs8    = (unsigned char*)p;   p += RPAD*512;      // 8,388,608
  float* partial_s       = (float*)p;           p += RTOT*4*4;      //   261,120
  float* picked          = (float*)p;           p += RTOT*4;        //    65,280
  if((size_t)(p - (char*)d_ws) > ws_size) return;  // workspace too small

  // K0: weight conversions
  k_transpose_cvt<0><<<dim3(40,16), 256, 0, stream>>>(W_proj, (unsigned char*)WprojT, 1280, 512);
  k_transpose_cvt<0><<<dim3(8,16),  256, 0, stream>>>(Wx,     (unsigned char*)WxT,    256,  512);
  k_cvt_whF<<<512, 256, 0, stream>>>(Wh, Wh8F);
  k_transpose_cvt<1><<<dim3(16,313),256, 0, stream>>>(W_out,  WoutT,                  512,  10000);
  k_cvt_bf16<<<320,   256, 0, stream>>>(feat,    featb, 64*1280);
  k_cvt_bf16<<<10000, 256, 0, stream>>>(W_embed, Wembb, 10000*256);

  // K1: h0
  k_h0<<<8, 256, 0, stream>>>(featb, WprojT, b_proj, h0b);
  // K2: xW
  k_xw<<<dim3(8, TS), 256, 0, stream>>>(Wembb, WxT, bvec, captions, xWb);
  // K3: RNN scan (fp8 Wh streamed, frag-major)
  k_rnn<<<4, 512, 0, stream>>>(h0b, Wh8F, xWb, hs8);
  // K4: fused scores + sumexp partials
  k_scores<<<dim3(4, 256), 256, 0, stream>>>(hs8, WoutT, b_out, partial_s);
  // K4b: picked scores
  k_picked<<<4080, 256, 0, stream>>>(hs8, WoutT, b_out, captions, picked);
  // K5: final loss
  k_loss<<<1, 256, 0, stream>>>(partial_s, picked, captions, (float*)d_out);
}

// Round 5
// 843.424 us; speedup vs baseline: 1.0846x; 1.0553x over previous
//
#include <hip/hip_runtime.h>

// Problem dims
#define NS 64      // batch
#define TT 256     // caption length
#define TS 255     // RNN timesteps (T-1)
#define VV 10000   // vocab
#define DF 1280    // feature dim
#define WD 256     // word-embed dim
#define HD 512     // hidden dim
#define RTOT (TS*NS)   // 16320 output rows (r = t*64 + n)
#define RPAD 16384     // padded rows for hs

typedef __attribute__((ext_vector_type(4))) float f32x4;
typedef __attribute__((ext_vector_type(8))) short s16x8;
typedef __attribute__((ext_vector_type(4))) unsigned int u32x4;
typedef __attribute__((ext_vector_type(2))) long s64x2;

__device__ __forceinline__ unsigned short f2bf(float f){
  unsigned u; __builtin_memcpy(&u, &f, 4);
  u += 0x7FFFu + ((u >> 16) & 1u);            // RNE
  return (unsigned short)(u >> 16);
}
__device__ __forceinline__ float bf2f(unsigned short h){
  unsigned u = ((unsigned)h) << 16; float f; __builtin_memcpy(&f, &u, 4); return f;
}
__device__ __forceinline__ unsigned char f2fp8(float f){
  int p = __builtin_amdgcn_cvt_pk_fp8_f32(f, f, 0, false);  // OCP e4m3
  return (unsigned char)(p & 0xFF);
}
__device__ __forceinline__ float dot4_fp8(unsigned int a, unsigned int b){
  float d;
  d  = __builtin_amdgcn_cvt_f32_fp8(a, 0) * __builtin_amdgcn_cvt_f32_fp8(b, 0);
  d += __builtin_amdgcn_cvt_f32_fp8(a, 1) * __builtin_amdgcn_cvt_f32_fp8(b, 1);
  d += __builtin_amdgcn_cvt_f32_fp8(a, 2) * __builtin_amdgcn_cvt_f32_fp8(b, 2);
  d += __builtin_amdgcn_cvt_f32_fp8(a, 3) * __builtin_amdgcn_cvt_f32_fp8(b, 3);
  return d;
}

// ---------------- K0: transpose + convert weights (fp32 [R][C] -> [C][R] bf16/fp8)
template<int FP8>
__global__ __launch_bounds__(256) void k_transpose_cvt(const float* __restrict__ src,
    unsigned char* __restrict__ dst, int R, int C){
  __shared__ float tile[32][33];
  int r0 = blockIdx.x*32, c0 = blockIdx.y*32;
  int tr = threadIdx.x >> 5, tc = threadIdx.x & 31;
  #pragma unroll
  for(int p=0;p<4;p++){
    int r = r0 + tr + p*8, c = c0 + tc;
    tile[tr + p*8][tc] = (r < R && c < C) ? src[r*C + c] : 0.f;
  }
  __syncthreads();
  #pragma unroll
  for(int p=0;p<4;p++){
    int oc = c0 + tr + p*8;   // dst row (C dim)
    int orow = r0 + tc;       // dst col (R dim)
    if(oc < C && orow < R){
      float v = tile[tc][tr + p*8];
      if(FP8) dst[oc*R + orow] = f2fp8(v);
      else ((unsigned short*)dst)[oc*R + orow] = f2bf(v);
    }
  }
}

// ---------------- K0w: Wh fp32 [k][j] -> Wh8S wave-order swizzled fp8.
// Byte i: w=i>>15, ct=(i>>13)&3, kcp=(i>>10)&7, lane=(i>>4)&63, lb=i&15;
// q=lane>>4, rr=lane&15, kc=2*kcp+(lb>>3), b=lb&7;
// value = fp8(Wh[(kc*32+q*8+b)*HD + (w*64+ct*16+rr)]).
// K3 then loads each B-frag-pair as one fully-coalesced 1KB wave instruction.
__global__ __launch_bounds__(256) void k_cvt_whS(const float* __restrict__ Wh,
    unsigned char* __restrict__ Wh8S){
  int i = blockIdx.x*256 + threadIdx.x;      // 1024 blocks -> 256K bytes
  int w = i>>15, ct = (i>>13)&3, kcp = (i>>10)&7, lane = (i>>4)&63, lb = i&15;
  int q = lane>>4, rr = lane&15;
  int kc = 2*kcp + (lb>>3), b = lb&7;
  int k = kc*32 + q*8 + b;
  int j = w*64 + ct*16 + rr;
  Wh8S[i] = f2fp8(Wh[k*HD + j]);
}

// ---------------- K0c: elementwise fp32 -> bf16
__global__ __launch_bounds__(256) void k_cvt_bf16(const float* __restrict__ src,
    unsigned short* __restrict__ dst, int n){
  int i = blockIdx.x*256 + threadIdx.x;
  if(i < n) dst[i] = f2bf(src[i]);
}

// ---------------- K1: h0 = feat @ W_proj + b_proj  -> bf16 [64][512]
__global__ __launch_bounds__(256) void k_h0(const unsigned short* __restrict__ featb,
    const unsigned short* __restrict__ WprojT, const float* __restrict__ b_proj,
    unsigned short* __restrict__ h0b){
  __shared__ unsigned short Al[64*264];
  __shared__ unsigned short Bl[64*264];
  int tid = threadIdx.x, cb = blockIdx.x;
  int w = tid>>6, lane = tid&63, q = lane>>4, rr = lane&15;
  f32x4 acc[4];
  #pragma unroll
  for(int i=0;i<4;i++){ acc[i][0]=0.f; acc[i][1]=0.f; acc[i][2]=0.f; acc[i][3]=0.f; }
  for(int kb=0; kb<5; kb++){
    {
      int row = tid >> 2, part = tid & 3;
      const u32x4* s = (const u32x4*)(featb + row*DF + kb*256 + part*64);
      u32x4* d = (u32x4*)(Al + row*264 + part*64);
      #pragma unroll
      for(int i=0;i<8;i++) d[i] = s[i];
    }
    {
      int row = tid >> 2, part = tid & 3;
      int j = cb*64 + row;
      const u32x4* s = (const u32x4*)(WprojT + j*DF + kb*256 + part*64);
      u32x4* d = (u32x4*)(Bl + row*264 + part*64);
      #pragma unroll
      for(int i=0;i<8;i++) d[i] = s[i];
    }
    __syncthreads();
    #pragma unroll
    for(int kc=0;kc<8;kc++){
      s16x8 a = *(const s16x8*)(Al + (w*16 + rr)*264 + kc*32 + q*8);
      #pragma unroll
      for(int tc=0;tc<4;tc++){
        s16x8 bb = *(const s16x8*)(Bl + (tc*16 + rr)*264 + kc*32 + q*8);
        acc[tc] = __builtin_amdgcn_mfma_f32_16x16x32_bf16(a, bb, acc[tc], 0, 0, 0);
      }
    }
    __syncthreads();
  }
  #pragma unroll
  for(int tc=0;tc<4;tc++){
    #pragma unroll
    for(int reg=0;reg<4;reg++){
      int n = w*16 + q*4 + reg;
      int j = cb*64 + tc*16 + rr;
      h0b[n*HD + j] = f2bf(acc[tc][reg] + b_proj[j]);
    }
  }
}

// ---------------- K2: xW[t][n][j] = W_embed[cap[n][t]] @ Wx + b  -> bf16
__global__ __launch_bounds__(256) void k_xw(const unsigned short* __restrict__ Wembb,
    const unsigned short* __restrict__ WxT, const float* __restrict__ bvec,
    const int* __restrict__ captions, unsigned short* __restrict__ xWb){
  __shared__ unsigned short Al[64*264];
  __shared__ unsigned short Bl[64*264];
  int tid = threadIdx.x, cb = blockIdx.x, t = blockIdx.y;
  int w = tid>>6, lane = tid&63, q = lane>>4, rr = lane&15;
  {
    int row = tid >> 2, part = tid & 3;
    int idx = captions[row*TT + t];
    const u32x4* s = (const u32x4*)(Wembb + idx*WD + part*64);
    u32x4* d = (u32x4*)(Al + row*264 + part*64);
    #pragma unroll
    for(int i=0;i<8;i++) d[i] = s[i];
  }
  {
    int row = tid >> 2, part = tid & 3;
    int j = cb*64 + row;
    const u32x4* s = (const u32x4*)(WxT + j*WD + part*64);
    u32x4* d = (u32x4*)(Bl + row*264 + part*64);
    #pragma unroll
    for(int i=0;i<8;i++) d[i] = s[i];
  }
  __syncthreads();
  f32x4 acc[4];
  #pragma unroll
  for(int i=0;i<4;i++){ acc[i][0]=0.f; acc[i][1]=0.f; acc[i][2]=0.f; acc[i][3]=0.f; }
  #pragma unroll
  for(int kc=0;kc<8;kc++){
    s16x8 a = *(const s16x8*)(Al + (w*16 + rr)*264 + kc*32 + q*8);
    #pragma unroll
    for(int tc=0;tc<4;tc++){
      s16x8 bb = *(const s16x8*)(Bl + (tc*16 + rr)*264 + kc*32 + q*8);
      acc[tc] = __builtin_amdgcn_mfma_f32_16x16x32_bf16(a, bb, acc[tc], 0, 0, 0);
    }
  }
  #pragma unroll
  for(int tc=0;tc<4;tc++){
    #pragma unroll
    for(int reg=0;reg<4;reg++){
      int n = w*16 + q*4 + reg;
      int j = cb*64 + tc*16 + rr;
      xWb[t*(NS*HD) + n*HD + j] = f2bf(acc[tc][reg] + bvec[j]);
    }
  }
}

// ---------------- K3: RNN scan. Wh fp8: half (ct=0,1 slabs, 128KB) resident in LDS,
// half (ct=2,3) streamed L2->VGPR as fully-coalesced 1KB wave loads.
// 4 WGs x 16 samples x 512 thr; h fp8 double-buffered in LDS; 1 barrier/step.
__global__ __launch_bounds__(512, 1) void k_rnn(const unsigned short* __restrict__ h0b,
    const unsigned char* __restrict__ Wh8S, const unsigned short* __restrict__ xWb,
    unsigned char* __restrict__ hs8){
  __shared__ unsigned char whl[131072];        // ct=0,1 slabs, wave-order
  __shared__ unsigned char hbuf[2][16*552];    // fp8 h, stride 552
  int tid = threadIdx.x, w = tid>>6, lane = tid&63, q = lane>>4, rr = lane&15;
  int n0 = blockIdx.x * 16;
  int j0 = w * 64;                             // 8 waves x 64 cols
  // preload LDS half of Wh (global blocks (w,ct<2) of 8KB -> LDS (w*2+ct)*8KB)
  #pragma unroll
  for(int i=0;i<16;i++){
    int o = (i*512 + tid)*16;
    int blk = o >> 13;
    int ww = blk >> 1, cc = blk & 1;
    int gsrc = (ww*4 + cc)*8192 + (o & 8191);
    *(u32x4*)(whl + o) = *(const u32x4*)(Wh8S + gsrc);
  }
  // init h (bf16 -> fp8) into hbuf[0]
  {
    int s = tid>>5, c0 = (tid&31)*16;
    #pragma unroll
    for(int i=0;i<16;i++)
      hbuf[0][s*552 + c0 + i] = f2fp8(bf2f(h0b[(n0+s)*HD + c0 + i]));
  }
  __syncthreads();
  const unsigned short* xwp = xWb + n0*HD;
  for(int t=0; t<TS; t++){
    const unsigned char* hb = hbuf[t&1];
    unsigned char*       hn = hbuf[(t&1)^1];
    // prefetch streamed B frags (ct=2,3): 1KB/wave per instr, 16 instrs
    s64x2 wst[2][8];
    #pragma unroll
    for(int c2=0;c2<2;c2++){
      const unsigned char* gb = Wh8S + (size_t)(w*4 + 2 + c2)*8192 + lane*16;
      #pragma unroll
      for(int kcp=0;kcp<8;kcp++)
        wst[c2][kcp] = *(const s64x2*)(gb + kcp*1024);
    }
    // xw for this step (epilogue-only use; full step of latency cover)
    float xwv[16];
    #pragma unroll
    for(int ct=0;ct<4;ct++)
      #pragma unroll
      for(int reg=0;reg<4;reg++)
        xwv[ct*4+reg] = bf2f(xwp[(q*4+reg)*HD + j0 + ct*16 + rr]);
    // A frags from LDS
    long af[16];
    #pragma unroll
    for(int kc=0;kc<16;kc++)
      af[kc] = *(const long*)(hb + rr*552 + kc*32 + q*8);
    f32x4 acc[4];
    #pragma unroll
    for(int ct=0;ct<4;ct++){ acc[ct][0]=0.f; acc[ct][1]=0.f; acc[ct][2]=0.f; acc[ct][3]=0.f; }
    // LDS-resident cts (0,1)
    #pragma unroll
    for(int ct=0;ct<2;ct++){
      const unsigned char* lb = whl + (w*2 + ct)*8192 + lane*16;
      #pragma unroll
      for(int kcp=0;kcp<8;kcp++){
        s64x2 wv = *(const s64x2*)(lb + kcp*1024);
        acc[ct] = __builtin_amdgcn_mfma_f32_16x16x32_fp8_fp8(af[2*kcp],   wv[0], acc[ct], 0,0,0);
        acc[ct] = __builtin_amdgcn_mfma_f32_16x16x32_fp8_fp8(af[2*kcp+1], wv[1], acc[ct], 0,0,0);
      }
    }
    // streamed cts (2,3)
    #pragma unroll
    for(int c2=0;c2<2;c2++)
      #pragma unroll
      for(int kcp=0;kcp<8;kcp++){
        acc[2+c2] = __builtin_amdgcn_mfma_f32_16x16x32_fp8_fp8(af[2*kcp],   wst[c2][kcp][0], acc[2+c2], 0,0,0);
        acc[2+c2] = __builtin_amdgcn_mfma_f32_16x16x32_fp8_fp8(af[2*kcp+1], wst[c2][kcp][1], acc[2+c2], 0,0,0);
      }
    #pragma unroll
    for(int ct=0;ct<4;ct++){
      int j = j0 + ct*16 + rr;
      #pragma unroll
      for(int reg=0;reg<4;reg++){
        int nl = q*4 + reg;
        float pre = acc[ct][reg] + xwv[ct*4+reg];
        float e2 = __builtin_amdgcn_exp2f(pre * 2.8853900817779268f); // e^(2x)
        float h = (e2 - 1.f) * __builtin_amdgcn_rcpf(e2 + 1.f);       // tanh
        unsigned char c = f2fp8(h);
        hs8[(size_t)(t*NS + n0 + nl)*HD + j] = c;
        hn[nl*552 + j] = c;
      }
    }
    __syncthreads();
    xwp += NS*HD;
  }
}

// ---------------- K4: fused scores GEMM (fp8) + sumexp partials.
// grid (4 chunks, 256 rowblocks of 64); 256 thr; 64-row B tiles -> 4 blocks/CU.
__global__ __launch_bounds__(256, 4) void k_scores(const unsigned char* __restrict__ hs8,
    const unsigned char* __restrict__ WoutT, const float* __restrict__ b_out,
    float* __restrict__ partial_s){
  __shared__ unsigned char Bl[64*528];
  __shared__ float sred[2][64];
  int tid = threadIdx.x;
  int chunk = blockIdx.x, rb = blockIdx.y;
  int w = tid>>6, lane = tid&63, q = lane>>4, rr = lane&15;
  int wi = w>>1, wj = w&1;          // wi: row half (32), wj: col half (32)
  long af[2][16];
  #pragma unroll
  for(int tr=0;tr<2;tr++)
    #pragma unroll
    for(int kc=0;kc<16;kc++){
      int row = rb*64 + wi*32 + tr*16 + rr;   // < RPAD always
      af[tr][kc] = *(const long*)(hs8 + (size_t)row*HD + kc*32 + q*8);
    }
  float sacc[8];
  #pragma unroll
  for(int i=0;i<8;i++) sacc[i]=0.f;
  int vc0 = chunk*2500, vc1 = vc0 + 2500;
  for(int vt=0; vt<40; vt++){
    int vbase = vc0 + vt*64;
    {
      int v = tid & 63, part = tid >> 6;
      int vg = vbase + v; if(vg > VV-1) vg = VV-1;
      const u32x4* s = (const u32x4*)(WoutT + (size_t)vg*HD + part*128);
      u32x4 t0=s[0],t1=s[1],t2=s[2],t3=s[3],t4=s[4],t5=s[5],t6=s[6],t7=s[7];
      u32x4* d = (u32x4*)(Bl + v*528 + part*128);
      d[0]=t0;d[1]=t1;d[2]=t2;d[3]=t3;d[4]=t4;d[5]=t5;d[6]=t6;d[7]=t7;
    }
    __syncthreads();
    f32x4 acc[2][2];
    #pragma unroll
    for(int a=0;a<2;a++)
      #pragma unroll
      for(int b=0;b<2;b++){ acc[a][b][0]=0.f; acc[a][b][1]=0.f; acc[a][b][2]=0.f; acc[a][b][3]=0.f; }
    #pragma unroll
    for(int kc=0;kc<16;kc++){
      long b0 = *(const long*)(Bl + (wj*32 +  0 + rr)*528 + kc*32 + q*8);
      long b1 = *(const long*)(Bl + (wj*32 + 16 + rr)*528 + kc*32 + q*8);
      acc[0][0] = __builtin_amdgcn_mfma_f32_16x16x32_fp8_fp8(af[0][kc], b0, acc[0][0], 0,0,0);
      acc[0][1] = __builtin_amdgcn_mfma_f32_16x16x32_fp8_fp8(af[0][kc], b1, acc[0][1], 0,0,0);
      acc[1][0] = __builtin_amdgcn_mfma_f32_16x16x32_fp8_fp8(af[1][kc], b0, acc[1][0], 0,0,0);
      acc[1][1] = __builtin_amdgcn_mfma_f32_16x16x32_fp8_fp8(af[1][kc], b1, acc[1][1], 0,0,0);
    }
    #pragma unroll
    for(int tc=0;tc<2;tc++){
      int vg = vbase + wj*32 + tc*16 + rr;
      bool vok = vg < vc1;
      float bo = vok ? b_out[vg] : 0.f;
      #pragma unroll
      for(int tr=0;tr<2;tr++)
        #pragma unroll
        for(int reg=0;reg<4;reg++){
          float sc = acc[tr][tc][reg] + bo;
          float ex = __builtin_amdgcn_exp2f(sc * 1.4426950408889634f);
          if(vok) sacc[tr*4+reg] += ex;
        }
    }
    __syncthreads();
  }
  #pragma unroll
  for(int i=0;i<8;i++){
    float v = sacc[i];
    v += __shfl_xor(v, 1, 64);
    v += __shfl_xor(v, 2, 64);
    v += __shfl_xor(v, 4, 64);
    v += __shfl_xor(v, 8, 64);
    sacc[i] = v;
  }
  if(rr == 0){
    #pragma unroll
    for(int tr=0;tr<2;tr++)
      #pragma unroll
      for(int reg=0;reg<4;reg++)
        sred[wj][wi*32 + tr*16 + q*4 + reg] = sacc[tr*4+reg];
  }
  __syncthreads();
  if(tid < 64){
    int row = rb*64 + tid;
    if(row < RTOT) partial_s[row*4 + chunk] = sred[0][tid] + sred[1][tid];
  }
}

// ---------------- K4b: picked[R] = score(R, y_R) ; one wave per row
__global__ __launch_bounds__(256) void k_picked(const unsigned char* __restrict__ hs8,
    const unsigned char* __restrict__ WoutT, const float* __restrict__ b_out,
    const int* __restrict__ captions, float* __restrict__ picked){
  int tid = threadIdx.x;
  int w = tid>>6, lane = tid&63;
  int R = blockIdx.x*4 + w;                 // 4080*4 = 16320 exact
  int t = R >> 6, n = R & 63;
  int y = captions[n*TT + t + 1];
  const unsigned int* hp = (const unsigned int*)(hs8 + (size_t)R*HD + lane*8);
  const unsigned int* wp = (const unsigned int*)(WoutT + (size_t)y*HD + lane*8);
  unsigned int hv0 = hp[0], hv1 = hp[1], wv0 = wp[0], wv1 = wp[1];
  float d = dot4_fp8(hv0, wv0) + dot4_fp8(hv1, wv1);
  d += __shfl_xor(d, 1, 64);
  d += __shfl_xor(d, 2, 64);
  d += __shfl_xor(d, 4, 64);
  d += __shfl_xor(d, 8, 64);
  d += __shfl_xor(d, 16, 64);
  d += __shfl_xor(d, 32, 64);
  if(lane == 0) picked[R] = d + b_out[y];
}

// ---------------- K5: loss = sum_masked(log(sum_s) - picked) / 64
__global__ __launch_bounds__(256) void k_loss(const float* __restrict__ partial_s,
    const float* __restrict__ picked, const int* __restrict__ captions,
    float* __restrict__ out){
  int tid = threadIdx.x;
  float a = 0.f;
  for(int R = tid; R < RTOT; R += 256){
    int t = R >> 6, n = R & 63;
    int y = captions[n*TT + t + 1];
    if(y != 0){
      float s = partial_s[R*4] + partial_s[R*4+1] + partial_s[R*4+2] + partial_s[R*4+3];
      a += __logf(s) - picked[R];
    }
  }
  a += __shfl_xor(a, 1, 64);
  a += __shfl_xor(a, 2, 64);
  a += __shfl_xor(a, 4, 64);
  a += __shfl_xor(a, 8, 64);
  a += __shfl_xor(a, 16, 64);
  a += __shfl_xor(a, 32, 64);
  __shared__ float red[4];
  int w = tid>>6, lane = tid&63;
  if(lane == 0) red[w] = a;
  __syncthreads();
  if(tid == 0) out[0] = (red[0]+red[1]+red[2]+red[3]) * (1.0f/64.0f);
}

extern "C" void kernel_launch(void* const* d_in, const int* in_sizes, int n_in,
                              void* d_out, int out_size, void* d_ws, size_t ws_size,
                              hipStream_t stream) {
  const float* feat    = (const float*)d_in[0];
  const float* W_proj  = (const float*)d_in[1];
  const float* b_proj  = (const float*)d_in[2];
  const float* W_embed = (const float*)d_in[3];
  const float* Wx      = (const float*)d_in[4];
  const float* Wh      = (const float*)d_in[5];
  const float* bvec    = (const float*)d_in[6];
  const float* W_out   = (const float*)d_in[7];
  const float* b_out   = (const float*)d_in[8];
  const int*   captions= (const int*)d_in[9];

  char* p = (char*)d_ws;
  unsigned short* WprojT = (unsigned short*)p;  p += 512*1280*2;    // 1,310,720
  unsigned short* WxT    = (unsigned short*)p;  p += 512*256*2;     //   262,144
  unsigned char*  Wh8S   = (unsigned char*)p;   p += 512*512;       //   262,144
  unsigned char*  WoutT  = (unsigned char*)p;   p += 10000*512;     // 5,120,000
  unsigned short* Wembb  = (unsigned short*)p;  p += 10000*256*2;   // 5,120,000
  unsigned short* featb  = (unsigned short*)p;  p += 64*1280*2;     //   163,840
  unsigned short* h0b    = (unsigned short*)p;  p += 64*512*2;      //    65,536
  unsigned short* xWb    = (unsigned short*)p;  p += TS*64*512*2;   //16,711,680
  unsigned char*  hs8    = (unsigned char*)p;   p += RPAD*512;      // 8,388,608
  float* partial_s       = (float*)p;           p += RTOT*4*4;      //   261,120
  float* picked          = (float*)p;           p += RTOT*4;        //    65,280
  if((size_t)(p - (char*)d_ws) > ws_size) return;  // workspace too small

  // K0: weight conversions
  k_transpose_cvt<0><<<dim3(40,16), 256, 0, stream>>>(W_proj, (unsigned char*)WprojT, 1280, 512);
  k_transpose_cvt<0><<<dim3(8,16),  256, 0, stream>>>(Wx,     (unsigned char*)WxT,    256,  512);
  k_cvt_whS<<<1024, 256, 0, stream>>>(Wh, Wh8S);
  k_transpose_cvt<1><<<dim3(16,313),256, 0, stream>>>(W_out,  WoutT,                  512,  10000);
  k_cvt_bf16<<<320,   256, 0, stream>>>(feat,    featb, 64*1280);
  k_cvt_bf16<<<10000, 256, 0, stream>>>(W_embed, Wembb, 10000*256);

  // K1: h0
  k_h0<<<8, 256, 0, stream>>>(featb, WprojT, b_proj, h0b);
  // K2: xW
  k_xw<<<dim3(8, TS), 256, 0, stream>>>(Wembb, WxT, bvec, captions, xWb);
  // K3: RNN scan (Wh fp8: half LDS-resident, half streamed coalesced)
  k_rnn<<<4, 512, 0, stream>>>(h0b, Wh8S, xWb, hs8);
  // K4: fused scores + sumexp partials
  k_scores<<<dim3(4, 256), 256, 0, stream>>>(hs8, WoutT, b_out, partial_s);
  // K4b: picked scores
  k_picked<<<4080, 256, 0, stream>>>(hs8, WoutT, b_out, captions, picked);
  // K5: final loss
  k_loss<<<1, 256, 0, stream>>>(partial_s, picked, captions, (float*)d_out);
}